// Round 4
// baseline (629.125 us; speedup 1.0000x reference)
//
#include <hip/hip_runtime.h>
#include <hip/hip_bf16.h>

#define LOG2F_ 0.69314718055994530942f

typedef __attribute__((ext_vector_type(8))) short s8bf;   // 8 bf16 (4 VGPRs)
typedef __attribute__((ext_vector_type(4))) float f32x4;  // MFMA C/D

// softplus(x) - log(2), numerically stable
__device__ __forceinline__ float ssp(float x) {
    float e = __expf(-fabsf(x));
    return __logf(1.0f + e) + fmaxf(x, 0.0f) - LOG2F_;
}
__device__ __forceinline__ short bf_hi(float x) {
    __hip_bfloat16 h = __float2bfloat16(x);
    return *reinterpret_cast<short*>(&h);
}
__device__ __forceinline__ float bf_to_f(short s) {
    __hip_bfloat16 h;
    *reinterpret_cast<short*>(&h) = s;
    return __bfloat162float(h);
}

// LDS (32 KB/block):
//   [0,8K)    W1_lo bf16, transposed [n][k] + XOR swizzle (shared by all waves)
//   [8K,16K)  W2_lo bf16, same layout
//   [16K,32K) 4 x 4KB per-wave buffers: Xh/Xl bf16 -> overlaid by h1 f32 -> overlaid by w f32
__global__ __launch_bounds__(256, 3) void edge_kernel(
    const float* __restrict__ bf, const float* __restrict__ eh,
    const float* __restrict__ W1, const float* __restrict__ b1,
    const float* __restrict__ W2, const float* __restrict__ b2,
    const int* __restrict__ dst,
    float* __restrict__ sums, float* __restrict__ cnt, int E)
{
    __shared__ __align__(16) unsigned char lds[32768];

    const int tid  = threadIdx.x;
    const int lane = tid & 63;
    const int wv   = tid >> 6;
    const int g    = lane >> 4;     // 16-lane group 0..3
    const int n16  = lane & 15;

    // ---- init: hi-weights -> register B-frags; lo-weights -> shared LDS ----
    s8bf w1h[4][2], w2h[4][2];
    {
        float* wst = (float*)(lds + 16384);   // 16KB scratch (wave-buf region)
        for (int i = tid; i < 4096; i += 256) wst[i] = W1[i];
        __syncthreads();
        #pragma unroll
        for (int nt = 0; nt < 4; ++nt)
            #pragma unroll
            for (int k0i = 0; k0i < 2; ++k0i)
                #pragma unroll
                for (int j = 0; j < 8; ++j)
                    w1h[nt][k0i][j] = bf_hi(wst[(k0i*32 + g*8 + j)*64 + nt*16 + n16]);
        for (int i = tid; i < 4096; i += 256) {
            int n = i & 63, k = i >> 6;
            float v = wst[k*64 + n];
            short hi = bf_hi(v);
            *(short*)(lds + n*128 + ((k*2) ^ ((n & 7) << 4))) = bf_hi(v - bf_to_f(hi));
        }
        __syncthreads();
        for (int i = tid; i < 4096; i += 256) wst[i] = W2[i];
        __syncthreads();
        #pragma unroll
        for (int nt = 0; nt < 4; ++nt)
            #pragma unroll
            for (int k0i = 0; k0i < 2; ++k0i)
                #pragma unroll
                for (int j = 0; j < 8; ++j)
                    w2h[nt][k0i][j] = bf_hi(wst[(k0i*32 + g*8 + j)*64 + nt*16 + n16]);
        for (int i = tid; i < 4096; i += 256) {
            int n = i & 63, k = i >> 6;
            float v = wst[k*64 + n];
            short hi = bf_hi(v);
            *(short*)(lds + 8192 + n*128 + ((k*2) ^ ((n & 7) << 4))) = bf_hi(v - bf_to_f(hi));
        }
        __syncthreads();   // last barrier — main loop is barrier-free
    }

    float b1v[4], b2v[4];
    #pragma unroll
    for (int nt = 0; nt < 4; ++nt) { b1v[nt] = b1[nt*16 + n16]; b2v[nt] = b2[nt*16 + n16]; }

    unsigned char* wbase = lds + 16384 + (wv << 12);   // 4KB per wave
    char* Xh = (char*)wbase;            // [16 rows][128B] swizzled bf16
    char* Xl = (char*)wbase + 2048;
    float* wlds = (float*)wbase;        // [16][64] f32 (overlays h1 after matmul2)
    const char* W1lo = (const char*)lds;
    const char* W2lo = (const char*)(lds + 8192);

    const int r4   = lane >> 2;          // staging row 0..15
    const int c16  = (lane & 3) << 4;    // staging col base
    const int s0   = (lane & 3) << 1;    // 16B slot base
    const int crow = g << 2;             // C-frag row base
    const int swz_n = (n16 & 7) << 4;

    const int wave_id = (blockIdx.x << 2) + wv;
    const int nwaves  = gridDim.x << 2;
    const int ntiles  = (E + 15) >> 4;

    // prologue: prefetch first tile's bf rows
    float xs[16];
    {
        const int t0 = wave_id;
        if (t0 < ntiles && (t0 << 4) + r4 < E) {
            const size_t roff = (size_t)((t0 << 4) + r4) * 64 + c16;
            *(float4*)&xs[0]  = *(const float4*)(bf + roff);
            *(float4*)&xs[4]  = *(const float4*)(bf + roff + 4);
            *(float4*)&xs[8]  = *(const float4*)(bf + roff + 8);
            *(float4*)&xs[12] = *(const float4*)(bf + roff + 12);
        } else {
            #pragma unroll
            for (int j = 0; j < 16; ++j) xs[j] = 0.f;
        }
    }

    for (int t = wave_id; t < ntiles; t += nwaves) {
        const int base = t << 4;

        // ---- split current X, stage to LDS ----
        s8bf hv0, hv1, lv0, lv1;
        #pragma unroll
        for (int j = 0; j < 8; ++j) {
            short h  = bf_hi(xs[j]);      hv0[j] = h;  lv0[j] = bf_hi(xs[j]     - bf_to_f(h));
            short h2 = bf_hi(xs[8 + j]);  hv1[j] = h2; lv1[j] = bf_hi(xs[8 + j] - bf_to_f(h2));
        }
        {
            const int sw = (r4 & 7) << 4;
            const int a0 = r4 * 128 + ((s0 << 4) ^ sw);
            const int a1 = r4 * 128 + (((s0 + 1) << 4) ^ sw);
            *(s8bf*)(Xh + a0) = hv0;  *(s8bf*)(Xh + a1) = hv1;
            *(s8bf*)(Xl + a0) = lv0;  *(s8bf*)(Xl + a1) = lv1;
        }

        // ---- prefetch next tile's bf (covers whole iteration) ----
        {
            const int tn = t + nwaves;
            if (tn < ntiles) {
                if ((tn << 4) + r4 < E) {
                    const size_t roff = (size_t)((tn << 4) + r4) * 64 + c16;
                    *(float4*)&xs[0]  = *(const float4*)(bf + roff);
                    *(float4*)&xs[4]  = *(const float4*)(bf + roff + 4);
                    *(float4*)&xs[8]  = *(const float4*)(bf + roff + 8);
                    *(float4*)&xs[12] = *(const float4*)(bf + roff + 12);
                } else {
                    #pragma unroll
                    for (int j = 0; j < 16; ++j) xs[j] = 0.f;
                }
            }
        }

        // ---- prefetch eh rows (consumed at scatter) + dst ----
        float evs[16];
        #pragma unroll
        for (int e = 0; e < 16; ++e) {
            int ge = base + e;
            evs[e] = (ge < E) ? eh[(size_t)ge * 64 + lane] : 0.f;
        }
        int dvec = 0;
        if (lane < 16 && base + lane < E) dvec = dst[base + lane];

        // ---- matmul 1: X @ W1 (hh + hl + lh) ----
        f32x4 acc[4];
        #pragma unroll
        for (int nt = 0; nt < 4; ++nt) acc[nt] = (f32x4){0.f, 0.f, 0.f, 0.f};
        #pragma unroll
        for (int k0i = 0; k0i < 2; ++k0i) {
            const int sA = (k0i << 2) + g;
            const int ab = n16 * 128 + ((sA << 4) ^ swz_n);
            s8bf ah = *(s8bf*)(Xh + ab);
            s8bf al = *(s8bf*)(Xl + ab);
            const int wb = (k0i << 6) + (g << 4);
            #pragma unroll
            for (int nt = 0; nt < 4; ++nt) {
                const int n = nt * 16 + n16;
                s8bf wl = *(const s8bf*)(W1lo + n * 128 + (wb ^ ((n & 7) << 4)));
                acc[nt] = __builtin_amdgcn_mfma_f32_16x16x32_bf16(ah, w1h[nt][k0i], acc[nt], 0, 0, 0);
                acc[nt] = __builtin_amdgcn_mfma_f32_16x16x32_bf16(ah, wl,           acc[nt], 0, 0, 0);
                acc[nt] = __builtin_amdgcn_mfma_f32_16x16x32_bf16(al, w1h[nt][k0i], acc[nt], 0, 0, 0);
            }
        }

        // ---- h1 = ssp(acc + b1) -> f32 LDS swizzled (overlays Xh/Xl) ----
        #pragma unroll
        for (int nt = 0; nt < 4; ++nt)
            #pragma unroll
            for (int r = 0; r < 4; ++r) {
                float h = ssp(acc[nt][r] + b1v[nt]);
                const int row = crow + r;
                *(float*)((char*)wbase + row * 256 + ((((nt * 16 + n16) << 2)) ^ ((row & 7) << 4))) = h;
            }

        // ---- matmul 2: h1 @ W2 (split A rebuilt from f32) ----
        f32x4 acc2[4];
        #pragma unroll
        for (int nt = 0; nt < 4; ++nt) acc2[nt] = (f32x4){0.f, 0.f, 0.f, 0.f};
        #pragma unroll
        for (int k0i = 0; k0i < 2; ++k0i) {
            const int bc = (k0i << 7) + (g << 5);
            const int rb = n16 << 8;
            f32x4 f0 = *(f32x4*)((char*)wbase + rb + (bc ^ swz_n));
            f32x4 f1 = *(f32x4*)((char*)wbase + rb + ((bc + 16) ^ swz_n));
            s8bf ah, al;
            #pragma unroll
            for (int j = 0; j < 4; ++j) {
                short h  = bf_hi(f0[j]); ah[j]     = h;  al[j]     = bf_hi(f0[j] - bf_to_f(h));
                short h2 = bf_hi(f1[j]); ah[4 + j] = h2; al[4 + j] = bf_hi(f1[j] - bf_to_f(h2));
            }
            const int wb = (k0i << 6) + (g << 4);
            #pragma unroll
            for (int nt = 0; nt < 4; ++nt) {
                const int n = nt * 16 + n16;
                s8bf wl = *(const s8bf*)(W2lo + n * 128 + (wb ^ ((n & 7) << 4)));
                acc2[nt] = __builtin_amdgcn_mfma_f32_16x16x32_bf16(ah, w2h[nt][k0i], acc2[nt], 0, 0, 0);
                acc2[nt] = __builtin_amdgcn_mfma_f32_16x16x32_bf16(ah, wl,           acc2[nt], 0, 0, 0);
                acc2[nt] = __builtin_amdgcn_mfma_f32_16x16x32_bf16(al, w2h[nt][k0i], acc2[nt], 0, 0, 0);
            }
        }

        // ---- w = ssp(acc2 + b2) -> [16][64] f32 (overlays h1; same-wave order) ----
        #pragma unroll
        for (int nt = 0; nt < 4; ++nt)
            #pragma unroll
            for (int r = 0; r < 4; ++r)
                wlds[(crow + r) * 64 + nt * 16 + n16] = ssp(acc2[nt][r] + b2v[nt]);

        // ---- scatter: full 256B row-atomic per edge, gate by eh in-flight ----
        #pragma unroll 4
        for (int e = 0; e < 16; ++e) {
            int ge = base + e;
            if (ge < E) {
                int d = __shfl(dvec, e, 64);
                atomicAdd(&sums[(size_t)d * 64 + lane], wlds[(e << 6) + lane] * evs[e]);
            }
        }
        if (lane < 16 && base + lane < E) atomicAdd(&cnt[dvec], 1.0f);
    }
}

// Node interaction block: h = sums/max(cnt,1); out = ssp(h@W3+b3)
__global__ __launch_bounds__(256) void node_kernel(
    const float* __restrict__ sums, const float* __restrict__ cnt,
    const float* __restrict__ W3, const float* __restrict__ b3,
    float* __restrict__ out, int N)
{
    __shared__ float sW[64][64];
    __shared__ float sb[64];
    __shared__ float sC[64];
    __shared__ float sX[64][65];

    const int tid = threadIdx.x;
    for (int i = tid; i < 4096; i += 256) sW[i >> 6][i & 63] = W3[i];
    if (tid < 64) sb[tid] = b3[tid];

    const int f4 = (tid & 15) << 2;
    const int e4 = (tid >> 4) << 2;
    const int ntiles = (N + 63) >> 6;

    for (int t = blockIdx.x; t < ntiles; t += gridDim.x) {
        const int base = t << 6;
        __syncthreads();
        if (tid < 64) {
            int gn = base + tid;
            sC[tid] = (gn < N) ? 1.0f / fmaxf(cnt[gn], 1.0f) : 0.0f;
        }
        __syncthreads();
        #pragma unroll
        for (int k = 0; k < 16; ++k) {
            int idx = (k << 8) + tid;
            int n = idx >> 6, r = idx & 63;
            int gn = base + n;
            sX[n][r] = (gn < N) ? sums[(size_t)gn * 64 + r] * sC[n] : 0.0f;
        }
        __syncthreads();

        float acc[4][4] = {{0.f,0.f,0.f,0.f},{0.f,0.f,0.f,0.f},
                           {0.f,0.f,0.f,0.f},{0.f,0.f,0.f,0.f}};
        #pragma unroll 8
        for (int r = 0; r < 64; ++r) {
            float xv[4];
            #pragma unroll
            for (int i = 0; i < 4; ++i) xv[i] = sX[e4 + i][r];
            float4 w4 = *(const float4*)&sW[r][f4];
            #pragma unroll
            for (int i = 0; i < 4; ++i) {
                acc[i][0] = fmaf(xv[i], w4.x, acc[i][0]);
                acc[i][1] = fmaf(xv[i], w4.y, acc[i][1]);
                acc[i][2] = fmaf(xv[i], w4.z, acc[i][2]);
                acc[i][3] = fmaf(xv[i], w4.w, acc[i][3]);
            }
        }

        #pragma unroll
        for (int i = 0; i < 4; ++i) {
            int gn = base + e4 + i;
            if (gn < N) {
                float4 o;
                o.x = ssp(acc[i][0] + sb[f4 + 0]);
                o.y = ssp(acc[i][1] + sb[f4 + 1]);
                o.z = ssp(acc[i][2] + sb[f4 + 2]);
                o.w = ssp(acc[i][3] + sb[f4 + 3]);
                *(float4*)&out[(size_t)gn * 64 + f4] = o;
            }
        }
    }
}

extern "C" void kernel_launch(void* const* d_in, const int* in_sizes, int n_in,
                              void* d_out, int out_size, void* d_ws, size_t ws_size,
                              hipStream_t stream) {
    const float* bf = (const float*)d_in[0];
    const float* eh = (const float*)d_in[1];
    const float* W1 = (const float*)d_in[2];
    const float* b1 = (const float*)d_in[3];
    const float* W2 = (const float*)d_in[4];
    const float* b2 = (const float*)d_in[5];
    const float* W3 = (const float*)d_in[6];
    const float* b3 = (const float*)d_in[7];
    const int*   dst = (const int*)d_in[8];

    const int E = in_sizes[0] / 64;
    const int N = out_size / 64;        // out is [N, 64]

    float* sums = (float*)d_ws;
    float* cnt  = sums + (size_t)N * 64;

    hipMemsetAsync(d_ws, 0, ((size_t)N * 64 + N) * sizeof(float), stream);

    edge_kernel<<<1024, 256, 0, stream>>>(bf, eh, W1, b1, W2, b2, dst, sums, cnt, E);

    const int ntilesN = (N + 63) >> 6;
    node_kernel<<<ntilesN, 256, 0, stream>>>(sums, cnt, W3, b3, (float*)d_out, N);
}